// Round 18
// baseline (106.672 us; speedup 1.0000x reference)
//
#include <hip/hip_runtime.h>

// Problem constants (match reference)
#define NB 32
#define CH 3
#define HH 768
#define WW 768

// Exact-packing work queue: 18432 tile-units (384 column-chains x 48 tiles
// of 16 rows), grid = 2048 blocks = EXACTLY 8 blocks/CU x 256 CU, 9 tiles
// per block. Single 18.2 KB LDS buffer, pair-swizzle, register prefetch,
// NT stores — byte-identical math to R12.
#define TW 64
#define TH 16
#define SW 72                   // staged width: [tw0-4, tw0+68)
#define SWP 76                  // LDS row stride
#define SH (TH + 4)             // 20 staged rows
#define CSTRIDE (SH * SWP)
#define NTC (WW / TW)           // 12
#define NCOL (NB * NTC)         // 384 column chains
#define TPC (HH / TH)           // 48 tiles per column
#define NWG 2048                // exact capacity, %8==0
#define TPB 9                   // tiles per block (18432 / 2048)
#define UNITS (SH * (SW / 4))   // 360 float4-units per tile

typedef float v4f __attribute__((ext_vector_type(4)));  // NT stores

// Pair-swap swizzle (R11, proven -91% conflicts): logical in-row float f at
// physical f ^ (((f>>5)&1)<<1); granules 8..15 store halves swapped.
__device__ inline int pswz(int s) { return s ^ (((s >> 5) & 1) << 1); }

__global__ __launch_bounds__(256) void colwarp_conv_kernel(
    const float* __restrict__ im,
    const float* __restrict__ flat,
    float* __restrict__ out)
{
    // XCD swizzle: XCD x owns wid in [x*256,(x+1)*256) = 2304 consecutive
    // tile-units = 48 columns = 4 whole images -> halo + L2 locality.
    const int d   = blockIdx.x;
    const int wid = (d & 7) * (NWG / 8) + (d >> 3);

    __shared__ float xs[CH][SH][SWP];   // 18240 B -> 8 blocks/CU

    const int tid = threadIdx.x;

    // ---- per-column state (reloaded when the chain crosses a column) ----
    int curcol = -1;
    int tw0 = 0;
    float Wm[3][3], sh3[3], K[5][5], bias[3];
    const float *cb0 = im, *cb1 = im, *cb2 = im;
    float *ob0 = out, *ob1 = out, *ob2 = out;

    const size_t plane = (size_t)HH * WW;

    // ---- staging unit descriptors (column-independent parts) ----
    int ur[2], uldso[2], uc4[2];
    bool uon[2], uswap[2];
#pragma unroll
    for (int ui = 0; ui < 2; ++ui) {
        const int u  = tid + 256 * ui;
        const int rr = u / (SW / 4);
        const int c4 = u - rr * (SW / 4);     // granule 0..17
        ur[ui]    = rr;
        uldso[ui] = rr * SWP + c4 * 4;
        uc4[ui]   = c4;
        uon[ui]   = (u < UNITS);
        uswap[ui] = ((c4 >> 3) & 1) != 0;
    }
    int ugw[2] = {0, 0};   // tw0-dependent, set on column change

    float4 vld[2][CH];
    bool vok[2];

#define STAGE_LOAD(TH0)                                                        \
    _Pragma("unroll")                                                          \
    for (int ui = 0; ui < 2; ++ui) {                                           \
        const int gh = (TH0) + ur[ui] - 2;                                     \
        const bool ok = uon[ui] && ((unsigned)gh < (unsigned)HH)               \
                                && ((unsigned)ugw[ui] < (unsigned)WW);         \
        vok[ui] = ok;                                                          \
        if (ok) {                                                              \
            const size_t off = (size_t)gh * WW + ugw[ui];                      \
            vld[ui][0] = *(const float4*)(cb0 + off);                          \
            vld[ui][1] = *(const float4*)(cb1 + off);                          \
            vld[ui][2] = *(const float4*)(cb2 + off);                          \
        }                                                                      \
    }

#define STAGE_WRITE()                                                          \
    _Pragma("unroll")                                                          \
    for (int ui = 0; ui < 2; ++ui) {                                           \
        if (uon[ui]) {                                                         \
            float4 m0 = make_float4(0.f, 0.f, 0.f, 0.f), m1 = m0, m2 = m0;     \
            if (vok[ui]) {                                                     \
                const float4 a0 = vld[ui][0], a1 = vld[ui][1], a2 = vld[ui][2];\
                m0.x = a0.x*Wm[0][0] + a1.x*Wm[1][0] + a2.x*Wm[2][0] + bias[0];\
                m0.y = a0.y*Wm[0][0] + a1.y*Wm[1][0] + a2.y*Wm[2][0] + bias[0];\
                m0.z = a0.z*Wm[0][0] + a1.z*Wm[1][0] + a2.z*Wm[2][0] + bias[0];\
                m0.w = a0.w*Wm[0][0] + a1.w*Wm[1][0] + a2.w*Wm[2][0] + bias[0];\
                m1.x = a0.x*Wm[0][1] + a1.x*Wm[1][1] + a2.x*Wm[2][1] + bias[1];\
                m1.y = a0.y*Wm[0][1] + a1.y*Wm[1][1] + a2.y*Wm[2][1] + bias[1];\
                m1.z = a0.z*Wm[0][1] + a1.z*Wm[1][1] + a2.z*Wm[2][1] + bias[1];\
                m1.w = a0.w*Wm[0][1] + a1.w*Wm[1][1] + a2.w*Wm[2][1] + bias[1];\
                m2.x = a0.x*Wm[0][2] + a1.x*Wm[1][2] + a2.x*Wm[2][2] + bias[2];\
                m2.y = a0.y*Wm[0][2] + a1.y*Wm[1][2] + a2.y*Wm[2][2] + bias[2];\
                m2.z = a0.z*Wm[0][2] + a1.z*Wm[1][2] + a2.z*Wm[2][2] + bias[2];\
                m2.w = a0.w*Wm[0][2] + a1.w*Wm[1][2] + a2.w*Wm[2][2] + bias[2];\
            }                                                                  \
            const bool sw = uswap[ui];                                         \
            const float4 w0 = sw ? make_float4(m0.z,m0.w,m0.x,m0.y) : m0;      \
            const float4 w1 = sw ? make_float4(m1.z,m1.w,m1.x,m1.y) : m1;      \
            const float4 w2 = sw ? make_float4(m2.z,m2.w,m2.x,m2.y) : m2;      \
            *(float4*)(&xs[0][0][0] + 0 * CSTRIDE + uldso[ui]) = w0;           \
            *(float4*)(&xs[0][0][0] + 1 * CSTRIDE + uldso[ui]) = w1;           \
            *(float4*)(&xs[0][0][0] + 2 * CSTRIDE + uldso[ui]) = w2;           \
        }                                                                      \
    }

    const int tx = tid & 15;   // 4 output cols
    const int ty = tid >> 4;   // 1 output row
    const int r0 = ty;

    const int offA = pswz(4 * tx + 2);
    const int offB = pswz(4 * tx + 4);
    const int offC = pswz(4 * tx + 6);
    const int offD = pswz(4 * tx + 8);

#define CONV_STORE(TH0)                                                        \
    {                                                                          \
        float acc[CH][4];                                                      \
        _Pragma("unroll")                                                      \
        for (int c = 0; c < CH; ++c)                                           \
            _Pragma("unroll")                                                  \
            for (int o = 0; o < 4; ++o) acc[c][o] = 0.f;                       \
        _Pragma("unroll")                                                      \
        for (int rr = 0; rr < 5; ++rr) {                                       \
            _Pragma("unroll")                                                  \
            for (int c = 0; c < CH; ++c) {                                     \
                const float* rowb = &xs[0][0][0] + c * CSTRIDE                 \
                                    + (r0 + rr) * SWP;                         \
                const float2 p0 = *(const float2*)(rowb + offA);               \
                const float2 p1 = *(const float2*)(rowb + offB);               \
                const float2 p2 = *(const float2*)(rowb + offC);               \
                const float2 p3 = *(const float2*)(rowb + offD);               \
                const float w8[8] = {p0.x, p0.y, p1.x, p1.y,                   \
                                     p2.x, p2.y, p3.x, p3.y};                  \
                _Pragma("unroll")                                              \
                for (int j = 0; j < 5; ++j) {                                  \
                    _Pragma("unroll")                                          \
                    for (int o = 0; o < 4; ++o)                                \
                        acc[c][o] += w8[o + j] * K[rr][j];                     \
                }                                                              \
            }                                                                  \
        }                                                                      \
        {                                                                      \
            const size_t obase = (size_t)((TH0) + r0) * WW + tw0 + tx * 4;     \
            v4f v0 = {acc[0][0], acc[0][1], acc[0][2], acc[0][3]};             \
            v4f v1 = {acc[1][0], acc[1][1], acc[1][2], acc[1][3]};             \
            v4f v2 = {acc[2][0], acc[2][1], acc[2][2], acc[2][3]};             \
            __builtin_nontemporal_store(v0, (v4f*)&ob0[obase]);                \
            __builtin_nontemporal_store(v1, (v4f*)&ob1[obase]);                \
            __builtin_nontemporal_store(v2, (v4f*)&ob2[obase]);                \
        }                                                                      \
    }

    // ---- 9-tile work loop with column-chain pipelining ----
#pragma unroll 1
    for (int ti = 0; ti < TPB; ++ti) {
        const int w    = wid * TPB + ti;
        const int col  = w / TPC;            // 0..383
        const int trow = w - col * TPC;      // 0..47
        const int th0  = trow * TH;

        if (col != curcol) {
            curcol = col;
            const int b  = col / NTC;
            const int tc = col - b * NTC;
            tw0 = tc * TW;
            // per-sample params (block-uniform -> scalar)
            const float* f = flat + b * 37;
#pragma unroll
            for (int i = 0; i < 3; ++i)
#pragma unroll
                for (int j = 0; j < 3; ++j) Wm[i][j] = f[i * 3 + j];
#pragma unroll
            for (int i = 0; i < 3; ++i) sh3[i] = f[9 + i];
#pragma unroll
            for (int i = 0; i < 5; ++i)
#pragma unroll
                for (int j = 0; j < 5; ++j) K[i][j] = f[12 + i * 5 + j];
#pragma unroll
            for (int c = 0; c < 3; ++c)
                bias[c] = sh3[0]*Wm[0][c] + sh3[1]*Wm[1][c] + sh3[2]*Wm[2][c];
            const float* cbase = im + (size_t)b * CH * plane;
            cb0 = cbase; cb1 = cbase + plane; cb2 = cbase + 2 * plane;
            float* obase = out + (size_t)b * CH * plane;
            ob0 = obase; ob1 = obase + plane; ob2 = obase + 2 * plane;
#pragma unroll
            for (int ui = 0; ui < 2; ++ui) ugw[ui] = tw0 - 4 + uc4[ui] * 4;
            // prologue: stage this tile
            STAGE_LOAD(th0);
            STAGE_WRITE();
            __syncthreads();
        }

        const bool more = (ti + 1 < TPB) && (trow != TPC - 1);
        if (more) { STAGE_LOAD(th0 + TH); }   // HBM issue hides under conv
        CONV_STORE(th0);
        __syncthreads();                       // all reads of buffer done
        if (more) {
            STAGE_WRITE();                     // mix + write next tile
            __syncthreads();                   // buffer ready
        }
    }
}

extern "C" void kernel_launch(void* const* d_in, const int* in_sizes, int n_in,
                              void* d_out, int out_size, void* d_ws, size_t ws_size,
                              hipStream_t stream) {
    const float* im   = (const float*)d_in[0];
    const float* flat = (const float*)d_in[1];
    float* out        = (float*)d_out;

    colwarp_conv_kernel<<<dim3(NWG), dim3(256), 0, stream>>>(im, flat, out);
}